// Round 7
// baseline (4483.896 us; speedup 1.0000x reference)
//
#include <hip/hip_runtime.h>
#include <math.h>

// ---------------------------------------------------------------------------
// TreeTextEmbed — numpy-faithful fp32 pipeline, round 7.
// vs r5/r6 (bit-identical failures): two numpy-internals fixes:
//  (1) np.mean pairwise: AVX512-dispatched leaves — 8 acc x 16 lanes per
//      128-leaf, ((r0+r1)+(r2+r3))+((r4+r5)+(r6+r7)) lanewise, then
//      _mm512_reduce_add_ps tree (xor 8,4,2,1), then (L0+L1)+(L2+L3).
//  (2) np.einsum: baseline SSE (W=4, NO FMA, mul+add), reverse-chained
//      4x unroll: per 16-block lane j order {12+j,8+j,4+j,j}; final
//      (c0+c1)+(c2+c3) via hadd.
// GEMMs: OpenBLAS sgemm model — fp32 FMA, k ascending, K-panels 384+128
// (r5==r6 proved panel split non-discriminating). Elementwise __f*_rn in
// numpy op order. Post-gate math (attention, final interp) relaxed.
// ---------------------------------------------------------------------------

__device__ __forceinline__ float fadd32(float a, float b) { return __fadd_rn(a, b); }
__device__ __forceinline__ float fmul32(float a, float b) { return __fmul_rn(a, b); }
__device__ __forceinline__ float fsub32(float a, float b) { return __fsub_rn(a, b); }
__device__ __forceinline__ float fdiv32(float a, float b) { return __fdiv_rn(a, b); }

// numpy pairwise sum of contiguous 512 floats, AVX512 model (see header).
// All 64 lanes return the same value.
__device__ __forceinline__ float np_pairwise512(const float* row, int lane) {
  const int L = lane >> 4, j = lane & 15;
  const float* p = row + 128 * L + j;
  const float r0 = p[0],  r1 = p[16], r2 = p[32],  r3 = p[48];
  const float r4 = p[64], r5 = p[80], r6 = p[96],  r7 = p[112];
  float v = fadd32(fadd32(fadd32(r0, r1), fadd32(r2, r3)),
                   fadd32(fadd32(r4, r5), fadd32(r6, r7)));
  // _mm512_reduce_add_ps tree within the 16-lane leaf
  v = fadd32(v, __shfl_xor(v, 8));
  v = fadd32(v, __shfl_xor(v, 4));
  v = fadd32(v, __shfl_xor(v, 2));
  v = fadd32(v, __shfl_xor(v, 1));
  // pairwise recursion: (L0+L1)+(L2+L3)
  v = fadd32(v, __shfl_xor(v, 16));
  v = fadd32(v, __shfl_xor(v, 32));
  return v;
}

// ---------------- K1: embed + LN + pool2 ----------------
__global__ __launch_bounds__(256) void k_embed(
    const int* __restrict__ text, const float* __restrict__ pe,
    const float* __restrict__ id_w, const float* __restrict__ id_b,
    const float* __restrict__ eg, const float* __restrict__ eb,
    float* __restrict__ fused) {
  __shared__ float rb[4][512];
  const int w = threadIdx.x >> 6;
  const int lane = threadIdx.x & 63;
  const int wid = blockIdx.x * 4 + w;  // row b*2048+t
  const int b = wid >> 11;
  const int t = wid & 2047;
  float fus[8];
#pragma unroll
  for (int ss = 0; ss < 2; ++ss) {
    const int s = 2 * t + ss;
    const float idv = (float)text[b * 4096 + s];
    float x[8];
#pragma unroll
    for (int k = 0; k < 8; ++k) {
      const int c = k * 64 + lane;
      x[k] = fadd32(fadd32(fmul32(idv, id_w[c]), id_b[c]), pe[(size_t)s * 512 + c]);
      rb[w][c] = x[k];
    }
    const float m = fmul32(np_pairwise512(rb[w], lane), 1.f / 512.f);
    float d[8];
#pragma unroll
    for (int k = 0; k < 8; ++k) {
      d[k] = fsub32(x[k], m);
      rb[w][k * 64 + lane] = fmul32(d[k], d[k]);
    }
    const float var = fmul32(np_pairwise512(rb[w], lane), 1.f / 512.f);
    const float sdev = __fsqrt_rn(fadd32(var, 1e-5f));
#pragma unroll
    for (int k = 0; k < 8; ++k) {
      const int c = k * 64 + lane;
      const float ln = fadd32(fmul32(fdiv32(d[k], sdev), eg[c]), eb[c]);
      fus[k] = ss ? fmul32(fadd32(fus[k], ln), 0.5f) : ln;
    }
  }
  const size_t row = (size_t)wid * 512;
#pragma unroll
  for (int k = 0; k < 8; ++k) fused[row + k * 64 + lane] = fus[k];
}

// ---- fused np-sgemm + spike gate + residual + LN.  OUT may alias X.
// K-panels [0,384)+[384,512); single ascending FMA chain per panel.
__global__ __launch_bounds__(256) void k_gemm_gate_ln(
    const float* __restrict__ X, const float* __restrict__ W,
    const float* __restrict__ bias, const float* __restrict__ th,
    const float* __restrict__ g, const float* __restrict__ bet,
    float* __restrict__ OUT) {
  __shared__ float Xs[16][512];  // 32 KB
  __shared__ float Ws[512][16];  // 32 KB, Ws[n][kk ^ (n&15)]
  __shared__ float zb[4][512];   // 8 KB
  const int tid = threadIdx.x;
  const int w = tid >> 6, lane = tid & 63;
  const size_t bm = (size_t)blockIdx.x * 16;
  for (int i = tid; i < 16 * 512; i += 256)
    Xs[i >> 9][i & 511] = X[bm * 512 + i];
  float accA[4][8], accB[4][8];
#pragma unroll
  for (int r = 0; r < 4; ++r)
#pragma unroll
    for (int j = 0; j < 8; ++j) { accA[r][j] = 0.f; accB[r][j] = 0.f; }

  auto inner = [&](float (&acc)[4][8], int k0) {
#pragma unroll 4
    for (int kk = 0; kk < 16; ++kk) {
      float xr[4];
#pragma unroll
      for (int r = 0; r < 4; ++r) xr[r] = Xs[w * 4 + r][k0 + kk];
#pragma unroll
      for (int j = 0; j < 8; ++j) {
        const int n = lane + 64 * j;
        const float wv = Ws[n][kk ^ (lane & 15)];
#pragma unroll
        for (int r = 0; r < 4; ++r) acc[r][j] = __fmaf_rn(xr[r], wv, acc[r][j]);
      }
    }
  };

  for (int k0 = 0; k0 < 512; k0 += 16) {
    __syncthreads();
    for (int i = tid; i < 512 * 16; i += 256) {
      const int n = i >> 4, kk = i & 15;
      Ws[n][kk ^ (n & 15)] = W[(size_t)n * 512 + k0 + kk];
    }
    __syncthreads();
    if (k0 < 384) inner(accA, k0); else inner(accB, k0);
  }
  // epilogue: C = P1 + P2; +bias; gate; +residual; numpy LN
#pragma unroll
  for (int r = 0; r < 4; ++r) {
    const int row = w * 4 + r;
    float z[8];
#pragma unroll
    for (int j = 0; j < 8; ++j) {
      const int n = lane + 64 * j;
      const float mm = fadd32(accA[r][j], accB[r][j]);
      const float p32 = fadd32(mm, bias[n]);
      const float gz = (p32 >= th[n]) ? p32 : 0.f;
      z[j] = fadd32(gz, Xs[row][n]);
      zb[w][n] = z[j];
    }
    const float m = fmul32(np_pairwise512(zb[w], lane), 1.f / 512.f);
    float d[8];
#pragma unroll
    for (int j = 0; j < 8; ++j) {
      d[j] = fsub32(z[j], m);
      zb[w][lane + 64 * j] = fmul32(d[j], d[j]);
    }
    const float var = fmul32(np_pairwise512(zb[w], lane), 1.f / 512.f);
    const float sdev = __fsqrt_rn(fadd32(var, 1e-5f));
#pragma unroll
    for (int j = 0; j < 8; ++j) {
      const int n = lane + 64 * j;
      OUT[(bm + row) * 512 + n] = fadd32(fmul32(fdiv32(d[j], sdev), g[n]), bet[n]);
    }
  }
}

// ---- qkv np-sgemm: OUT[M,1536] = X[M,512]@W^T (panels 384+128) + bias ----
__global__ __launch_bounds__(256) void k_gemm_bias(
    const float* __restrict__ X, const float* __restrict__ W,
    const float* __restrict__ bias, float* __restrict__ OUT) {
  __shared__ float Xs[8][512];   // 16 KB
  __shared__ float Ws[1536][8];  // 48 KB, Ws[n][kk ^ (n&7)]
  const int tid = threadIdx.x;
  const int w = tid >> 6, lane = tid & 63;
  const size_t bm = (size_t)blockIdx.x * 8;
  for (int i = tid; i < 8 * 512; i += 256)
    Xs[i >> 9][i & 511] = X[bm * 512 + i];
  float accA[2][24], accB[2][24];
#pragma unroll
  for (int r = 0; r < 2; ++r)
#pragma unroll
    for (int j = 0; j < 24; ++j) { accA[r][j] = 0.f; accB[r][j] = 0.f; }

  auto inner = [&](float (&acc)[2][24], int k0) {
#pragma unroll
    for (int kk = 0; kk < 8; ++kk) {
      float xr[2];
#pragma unroll
      for (int r = 0; r < 2; ++r) xr[r] = Xs[w * 2 + r][k0 + kk];
#pragma unroll
      for (int j = 0; j < 24; ++j) {
        const int n = lane + 64 * j;
        const float wv = Ws[n][kk ^ (lane & 7)];
#pragma unroll
        for (int r = 0; r < 2; ++r) acc[r][j] = __fmaf_rn(xr[r], wv, acc[r][j]);
      }
    }
  };

  for (int k0 = 0; k0 < 512; k0 += 8) {
    __syncthreads();
    for (int i = tid; i < 1536 * 8; i += 256) {
      const int n = i >> 3, kk = i & 7;
      Ws[n][kk ^ (n & 7)] = W[(size_t)n * 512 + k0 + kk];
    }
    __syncthreads();
    if (k0 < 384) inner(accA, k0); else inner(accB, k0);
  }
#pragma unroll
  for (int r = 0; r < 2; ++r) {
    const int row = w * 2 + r;
#pragma unroll
    for (int j = 0; j < 24; ++j) {
      const int n = lane + 64 * j;
      OUT[(bm + row) * 1536 + n] = fadd32(fadd32(accA[r][j], accB[r][j]), bias[n]);
    }
  }
}

// ---------------- mean-pool groups of 4 rows (np slice-add order) ----------
__global__ __launch_bounds__(256) void k_pool4(
    const float* __restrict__ in, float* __restrict__ out) {
  const int idx = blockIdx.x * 256 + threadIdx.x;  // 16384*512 elements
  const int r = idx >> 9, c = idx & 511;
  const size_t base = (size_t)r * 2048 + c;
  const float s = fadd32(fadd32(fadd32(in[base], in[base + 512]), in[base + 1024]),
                         in[base + 1536]);
  out[idx] = fmul32(s, 0.25f);
}

// ---------------- transpose node weights: nwT[n][d][e] = nw[n][e][d] --------
__global__ __launch_bounds__(256) void k_transpose_nw(
    const float* __restrict__ nw, float* __restrict__ nwT) {
  const int idx = blockIdx.x * 256 + threadIdx.x;
  if (idx >= 15 * 4096) return;
  const int n = idx >> 12;
  const int e = (idx >> 6) & 63;
  const int d = idx & 63;
  nwT[(n << 12) + (d << 6) + e] = nw[idx];
}

// numpy einsum baseline-SSE model: W=4, no FMA (mul then add), reverse-chained
// 4x unroll — per 16-block, lane j consumes d in order {12+j, 8+j, 4+j, j};
// single accumulator per lane; final hadd: (c0+c1)+(c2+c3).
#define NP_EINSUM64(inp, wp, out_)                                          \
  {                                                                         \
    float c0 = 0.f, c1 = 0.f, c2 = 0.f, c3 = 0.f;                           \
    _Pragma("unroll")                                                       \
    for (int q_ = 0; q_ < 4; ++q_) {                                        \
      const int b_ = 16 * q_;                                               \
      _Pragma("unroll")                                                     \
      for (int u_ = 3; u_ >= 0; --u_) {                                     \
        const int d0_ = b_ + 4 * u_;                                        \
        c0 = fadd32(fmul32(__shfl(inp, d0_ + 0), wp[(d0_ + 0) << 6]), c0);  \
        c1 = fadd32(fmul32(__shfl(inp, d0_ + 1), wp[(d0_ + 1) << 6]), c1);  \
        c2 = fadd32(fmul32(__shfl(inp, d0_ + 2), wp[(d0_ + 2) << 6]), c2);  \
        c3 = fadd32(fmul32(__shfl(inp, d0_ + 3), wp[(d0_ + 3) << 6]), c3);  \
      }                                                                     \
    }                                                                       \
    out_ = fadd32(fadd32(c0, c1), fadd32(c2, c3));                          \
  }

// ---------------- fused spiking tree: K and V passes, fp32 states in LDS ----
__global__ __launch_bounds__(256) void k_tree(
    const float* __restrict__ QKV, const float* __restrict__ nwT,
    const float* __restrict__ nb, const float* __restrict__ th,
    const float* __restrict__ tau, const float* __restrict__ vr,
    float* __restrict__ TK, float* __restrict__ TV) {
  __shared__ float st0[8][8][64];
  __shared__ float st1[4][8][64];
  __shared__ float st2[2][8][64];
  __shared__ float st3[8][64];
  __shared__ float outA[8][8][64];
  __shared__ float outB[4][8][64];
  const int tid = threadIdx.x, w = tid >> 6, lane = tid & 63;
  const int sq = blockIdx.x & 3, bh = blockIdx.x >> 2;
  const int b = bh >> 3, h = bh & 7;
  for (int pass = 0; pass < 2; ++pass) {
    const int koff = 512 + pass * 512;
    // level 0: nodes 7..14
    for (int r = w; r < 64; r += 4) {
      const int n = r >> 3, sl = r & 7, sg = sq * 8 + sl;
      const float inp = QKV[((size_t)(b * 512 + n * 32 + sg)) * 1536 + koff + h * 64 + lane];
      const int node = 7 + n, pc = node * 64 + lane;
      const float* wp = nwT + node * 4096 + lane;
      float tot;
      NP_EINSUM64(inp, wp, tot);
      const float proj = fadd32(tot, nb[pc]);
      const float v = pass ? fadd32(fmul32(tau[pc], st0[n][sl][lane]), proj) : proj;
      const bool sp = v >= th[pc];
      if (!pass) st0[n][sl][lane] = sp ? vr[pc] : v;
      outA[n][sl][lane] = sp ? proj : 0.f;
    }
    __syncthreads();
    // level 1: nodes 3..6
    for (int r = w; r < 32; r += 4) {
      const int n = r >> 3, sl = r & 7;
      const float inp = fmul32(0.5f, fadd32(outA[2 * n][sl][lane], outA[2 * n + 1][sl][lane]));
      const int node = 3 + n, pc = node * 64 + lane;
      const float* wp = nwT + node * 4096 + lane;
      float tot;
      NP_EINSUM64(inp, wp, tot);
      const float proj = fadd32(tot, nb[pc]);
      const float v = pass ? fadd32(fmul32(tau[pc], st1[n][sl][lane]), proj) : proj;
      const bool sp = v >= th[pc];
      if (!pass) st1[n][sl][lane] = sp ? vr[pc] : v;
      outB[n][sl][lane] = sp ? proj : 0.f;
    }
    __syncthreads();
    // level 2: nodes 1..2 (reuse outA)
    for (int r = w; r < 16; r += 4) {
      const int n = r >> 3, sl = r & 7;
      const float inp = fmul32(0.5f, fadd32(outB[2 * n][sl][lane], outB[2 * n + 1][sl][lane]));
      const int node = 1 + n, pc = node * 64 + lane;
      const float* wp = nwT + node * 4096 + lane;
      float tot;
      NP_EINSUM64(inp, wp, tot);
      const float proj = fadd32(tot, nb[pc]);
      const float v = pass ? fadd32(fmul32(tau[pc], st2[n][sl][lane]), proj) : proj;
      const bool sp = v >= th[pc];
      if (!pass) st2[n][sl][lane] = sp ? vr[pc] : v;
      outA[n][sl][lane] = sp ? proj : 0.f;
    }
    __syncthreads();
    // level 3: root node 0 -> TK / TV
    for (int r = w; r < 8; r += 4) {
      const int sl = r & 7, sg = sq * 8 + sl;
      const float inp = fmul32(0.5f, fadd32(outA[0][sl][lane], outA[1][sl][lane]));
      const int pc = lane;
      const float* wp = nwT + lane;
      float tot;
      NP_EINSUM64(inp, wp, tot);
      const float proj = fadd32(tot, nb[pc]);
      const float v = pass ? fadd32(fmul32(tau[pc], st3[sl][lane]), proj) : proj;
      const bool sp = v >= th[pc];
      if (!pass) st3[sl][lane] = sp ? vr[pc] : v;
      float* dst = pass ? TV : TK;
      dst[((size_t)bh * 32 + sg) * 64 + lane] = sp ? proj : 0.f;
    }
    __syncthreads();
  }
}

// ---------------- attention (continuous; relaxed precision) ----------------
__global__ __launch_bounds__(256) void k_attn(
    const float* __restrict__ qkv, const float* __restrict__ treeK,
    const float* __restrict__ treeV, float* __restrict__ attn) {
  __shared__ float Ks[32][65];
  __shared__ float Vs[32][64];
  __shared__ float qs[4][64];
  const int tid = threadIdx.x;
  const int bh = blockIdx.x >> 7;
  const int lq0 = (blockIdx.x & 127) * 4;
  const int b = bh >> 3, h = bh & 7;
  for (int i = tid; i < 2048; i += 256) {
    const int j = i >> 6, d = i & 63;
    Ks[j][d] = treeK[((size_t)bh * 32 + j) * 64 + d];
    Vs[j][d] = treeV[((size_t)bh * 32 + j) * 64 + d];
  }
  {
    const int w = tid >> 6, d = tid & 63;
    qs[w][d] = qkv[((size_t)(b * 512) + lq0 + w) * 1536 + h * 64 + d];
  }
  __syncthreads();
  const int w = tid >> 6;
  const int lane = tid & 63;
  const int j = lane & 31;
  double scd = 0.0;
#pragma unroll
  for (int d = 0; d < 64; ++d) scd = fma((double)qs[w][d], (double)Ks[j][d], scd);
  float sc = fmul32((float)scd, 0.125f);
  float m = sc;
#pragma unroll
  for (int k = 1; k < 32; k <<= 1) m = fmaxf(m, __shfl_xor(m, k));
  float p = expf(fsub32(sc, m));
  float sum = p;
#pragma unroll
  for (int k = 1; k < 32; k <<= 1) sum += __shfl_xor(sum, k);
  p = fdiv32(p, sum);
  double accd = 0.0;
#pragma unroll
  for (int jj = 0; jj < 32; ++jj)
    accd = fma((double)__shfl(p, jj), (double)Vs[jj][lane], accd);
  attn[((size_t)(b * 512) + lq0 + w) * 512 + h * 64 + lane] = (float)accd;
}

// ---------------- final residual + LN (numpy-faithful) ----------------
__global__ __launch_bounds__(256) void k_add_ln(
    const float* __restrict__ A, const float* __restrict__ F,
    const float* __restrict__ g, const float* __restrict__ bet,
    float* __restrict__ O, int nrows) {
  __shared__ float zb[4][512];
  const int w = threadIdx.x >> 6;
  const int lane = threadIdx.x & 63;
  const int wid = blockIdx.x * 4 + w;
  if (wid >= nrows) return;
  const size_t row = (size_t)wid * 512;
  float z[8];
#pragma unroll
  for (int k = 0; k < 8; ++k) {
    const int c = k * 64 + lane;
    z[k] = fadd32(A[row + c], F[row + c]);
    zb[w][c] = z[k];
  }
  const float m = fmul32(np_pairwise512(zb[w], lane), 1.f / 512.f);
  float d[8];
#pragma unroll
  for (int k = 0; k < 8; ++k) {
    d[k] = fsub32(z[k], m);
    zb[w][k * 64 + lane] = fmul32(d[k], d[k]);
  }
  const float var = fmul32(np_pairwise512(zb[w], lane), 1.f / 512.f);
  const float sdev = __fsqrt_rn(fadd32(var, 1e-5f));
#pragma unroll
  for (int k = 0; k < 8; ++k) {
    const int c = k * 64 + lane;
    O[row + c] = fadd32(fmul32(fdiv32(d[k], sdev), g[c]), bet[c]);
  }
}

// ---------------- linear interpolation 512 -> 4096 rows ----------------
__global__ __launch_bounds__(256) void k_interp(
    const float* __restrict__ rows, float* __restrict__ out) {
  const int wid = blockIdx.x * 4 + (threadIdx.x >> 6);  // b*4096+s
  const int lane = threadIdx.x & 63;
  const int b = wid >> 12;
  const int s = wid & 4095;
  const double src = fmax(((double)s + 0.5) * 0.125 - 0.5, 0.0);
  const int i0 = (int)src;
  const int i1 = min(i0 + 1, 511);
  const double w1 = src - (double)i0;
  const double w0 = 1.0 - w1;
  const size_t r0 = ((size_t)b * 512 + i0) * 512;
  const size_t r1 = ((size_t)b * 512 + i1) * 512;
  const size_t o = (size_t)wid * 512;
#pragma unroll
  for (int k = 0; k < 2; ++k) {
    const int c4 = lane + 64 * k;
    const float4 a = *reinterpret_cast<const float4*>(&rows[r0 + (size_t)c4 * 4]);
    const float4 c = *reinterpret_cast<const float4*>(&rows[r1 + (size_t)c4 * 4]);
    float4 r;
    r.x = (float)((double)a.x * w0 + (double)c.x * w1);
    r.y = (float)((double)a.y * w0 + (double)c.y * w1);
    r.z = (float)((double)a.z * w0 + (double)c.z * w1);
    r.w = (float)((double)a.w * w0 + (double)c.w * w1);
    *reinterpret_cast<float4*>(&out[o + (size_t)c4 * 4]) = r;
  }
}

extern "C" void kernel_launch(void* const* d_in, const int* in_sizes, int n_in,
                              void* d_out, int out_size, void* d_ws, size_t ws_size,
                              hipStream_t stream) {
  const int*   text    = (const int*)d_in[0];
  const float* pe      = (const float*)d_in[1];
  const float* id_w    = (const float*)d_in[2];
  const float* id_b    = (const float*)d_in[3];
  const float* eg      = (const float*)d_in[4];
  const float* ebeta   = (const float*)d_in[5];
  const float* sub_w   = (const float*)d_in[6];
  const float* sub_b   = (const float*)d_in[7];
  const float* sub_th  = (const float*)d_in[8];
  const float* sub_ng  = (const float*)d_in[11];
  const float* sub_nb  = (const float*)d_in[12];
  const float* word_w  = (const float*)d_in[13];
  const float* word_b  = (const float*)d_in[14];
  const float* word_th = (const float*)d_in[15];
  const float* word_ng = (const float*)d_in[18];
  const float* word_nb = (const float*)d_in[19];
  const float* qkv_w   = (const float*)d_in[20];
  const float* qkv_b   = (const float*)d_in[21];
  const float* node_w  = (const float*)d_in[22];
  const float* node_b  = (const float*)d_in[23];
  const float* node_th = (const float*)d_in[24];
  const float* node_tau= (const float*)d_in[25];
  const float* node_vr = (const float*)d_in[26];
  const float* out_ng  = (const float*)d_in[27];
  const float* out_nb  = (const float*)d_in[28];

  float* O   = (float*)d_out;   // 67,108,864 floats
  float* WSF = (float*)d_ws;

  // d_out regions (floats)
  float* FU  = O;               // fused1 -> sub, in place [0 : 33554432)
  float* WD  = O + 33554432;    // word [33554432 : 41943040)
  float* QKV = O + 41943040;    // qkv  [41943040 : 67108864)

  // ws regions (floats)
  float* W1   = WSF;            // [0 : 8388608)  (dead after word GEMM)
  float* NWT  = WSF + 8388608;
  float* TK   = WSF + 8450048;
  float* TV   = WSF + 8974336;
  float* ROWS = WSF + 9498624;
  float* ATT  = WSF;            // reuses W1 space

  // 1. embed + LN + pool2 -> FU
  k_embed<<<16384, 256, 0, stream>>>(text, pe, id_w, id_b, eg, ebeta, FU);
  // 2. sub = LN(gate(FU @ sub_w^T + b) + FU), in place
  k_gemm_gate_ln<<<4096, 256, 0, stream>>>(FU, sub_w, sub_b, sub_th,
                                           sub_ng, sub_nb, FU);
  // 3. W1 = pool4(sub)
  k_pool4<<<32768, 256, 0, stream>>>(FU, W1);
  // 4. word = LN(gate(W1 @ word_w^T + b) + W1) -> WD
  k_gemm_gate_ln<<<1024, 256, 0, stream>>>(W1, word_w, word_b, word_th,
                                           word_ng, word_nb, WD);
  // 5. QKV = word @ qkv_w^T + b
  k_gemm_bias<<<2048, 256, 0, stream>>>(WD, qkv_w, qkv_b, QKV);
  // 6. node weight transpose
  k_transpose_nw<<<240, 256, 0, stream>>>(node_w, NWT);
  // 7. fused spiking tree (K + V passes, states in LDS) -> TK, TV
  k_tree<<<1024, 256, 0, stream>>>(QKV, NWT, node_b, node_th,
                                   node_tau, node_vr, TK, TV);
  // 8. attention -> ATT ([B,L,D] head-interleaved; overwrites dead W1)
  k_attn<<<32768, 256, 0, stream>>>(QKV, TK, TV, ATT);
  // 9. rows = LN(ATT + word) -> ROWS
  k_add_ln<<<4096, 256, 0, stream>>>(ATT, WD, out_ng, out_nb, ROWS, 16384);
  // 10. interpolate 512 -> 4096 rows, full fp32 d_out overwrite
  k_interp<<<32768, 256, 0, stream>>>(ROWS, O);
}

// Round 8
// 2866.513 us; speedup vs baseline: 1.5642x; 1.5642x over previous
//
#include <hip/hip_runtime.h>
#include <math.h>

// ---------------------------------------------------------------------------
// TreeTextEmbed — numpy-faithful fp32 pipeline, round 8 (first perf round).
// NUMERICS FROZEN (r7 passed): every gate-feeding path keeps bit sequences:
//   GEMM: per-element ascending-k fp32 FMA chain, K-panels [0,384)+[384,512),
//         C = fadd32(accA,accB); +bias; gate compare in fp32.
//   np.mean: AVX512 pairwise model (np_pairwise512).
//   einsum: baseline-SSE reverse-unrolled model (NP_EINSUM64).
// PERF CHANGES vs r7 (no numeric change):
//   - weights pre-transposed to WT[K][N]; GEMM LDS = Ws[kk][n] -> all inner
//     reads are contiguous ds_read_b128, conflict-free (was 8-way conflicts,
//     6.0e8 SQ_LDS_BANK_CONFLICT, VALUBusy 26%).
//   - BM=32 rows/block (was 8/16) -> W re-read cut 4x; b128 X reads.
//   - gate+bias stays in GEMM epilogue; residual+LN unfused into k_add_ln
//     (bit-identical op sequence, row-local).
//   - attention dots fp64 -> fp32 (post-gate continuous path).
// ---------------------------------------------------------------------------

__device__ __forceinline__ float fadd32(float a, float b) { return __fadd_rn(a, b); }
__device__ __forceinline__ float fmul32(float a, float b) { return __fmul_rn(a, b); }
__device__ __forceinline__ float fsub32(float a, float b) { return __fsub_rn(a, b); }
__device__ __forceinline__ float fdiv32(float a, float b) { return __fdiv_rn(a, b); }

// numpy pairwise sum of contiguous 512 floats, AVX512 model.
__device__ __forceinline__ float np_pairwise512(const float* row, int lane) {
  const int L = lane >> 4, j = lane & 15;
  const float* p = row + 128 * L + j;
  const float r0 = p[0],  r1 = p[16], r2 = p[32],  r3 = p[48];
  const float r4 = p[64], r5 = p[80], r6 = p[96],  r7 = p[112];
  float v = fadd32(fadd32(fadd32(r0, r1), fadd32(r2, r3)),
                   fadd32(fadd32(r4, r5), fadd32(r6, r7)));
  v = fadd32(v, __shfl_xor(v, 8));
  v = fadd32(v, __shfl_xor(v, 4));
  v = fadd32(v, __shfl_xor(v, 2));
  v = fadd32(v, __shfl_xor(v, 1));
  v = fadd32(v, __shfl_xor(v, 16));
  v = fadd32(v, __shfl_xor(v, 32));
  return v;
}

// ---------------- K1: embed + LN + pool2 (unchanged, bit-path) ----------------
__global__ __launch_bounds__(256) void k_embed(
    const int* __restrict__ text, const float* __restrict__ pe,
    const float* __restrict__ id_w, const float* __restrict__ id_b,
    const float* __restrict__ eg, const float* __restrict__ eb,
    float* __restrict__ fused) {
  __shared__ float rb[4][512];
  const int w = threadIdx.x >> 6;
  const int lane = threadIdx.x & 63;
  const int wid = blockIdx.x * 4 + w;  // row b*2048+t
  const int b = wid >> 11;
  const int t = wid & 2047;
  float fus[8];
#pragma unroll
  for (int ss = 0; ss < 2; ++ss) {
    const int s = 2 * t + ss;
    const float idv = (float)text[b * 4096 + s];
    float x[8];
#pragma unroll
    for (int k = 0; k < 8; ++k) {
      const int c = k * 64 + lane;
      x[k] = fadd32(fadd32(fmul32(idv, id_w[c]), id_b[c]), pe[(size_t)s * 512 + c]);
      rb[w][c] = x[k];
    }
    const float m = fmul32(np_pairwise512(rb[w], lane), 1.f / 512.f);
    float d[8];
#pragma unroll
    for (int k = 0; k < 8; ++k) {
      d[k] = fsub32(x[k], m);
      rb[w][k * 64 + lane] = fmul32(d[k], d[k]);
    }
    const float var = fmul32(np_pairwise512(rb[w], lane), 1.f / 512.f);
    const float sdev = __fsqrt_rn(fadd32(var, 1e-5f));
#pragma unroll
    for (int k = 0; k < 8; ++k) {
      const int c = k * 64 + lane;
      const float ln = fadd32(fmul32(fdiv32(d[k], sdev), eg[c]), eb[c]);
      fus[k] = ss ? fmul32(fadd32(fus[k], ln), 0.5f) : ln;
    }
  }
  const size_t row = (size_t)wid * 512;
#pragma unroll
  for (int k = 0; k < 8; ++k) fused[row + k * 64 + lane] = fus[k];
}

// ---------------- tiled weight transpose: WT[k][n] = W[n][k], K=512 ----------
__global__ __launch_bounds__(256) void k_transpose_w(
    const float* __restrict__ W, float* __restrict__ WT, int Nn) {
  __shared__ float t[32][33];
  const int n0 = blockIdx.x * 32, k0 = blockIdx.y * 32;
  const int li = threadIdx.x & 31, wi = threadIdx.x >> 5;
  for (int r = wi; r < 32; r += 8)
    t[r][li] = W[(size_t)(n0 + r) * 512 + k0 + li];
  __syncthreads();
  for (int r = wi; r < 32; r += 8)
    WT[(size_t)(k0 + r) * Nn + n0 + li] = t[li][r];
}

// ---- unified np-sgemm from WT[K][N]: OUT = [gate](X @ W^T + bias)
// BM=32, BN=256, BK=32; 256 thr; per-thread 8 rows x 4 cols.
// Chain per element: k ascending, panels [0,384)+[384,512)  (bit-frozen).
#define GEMM_INNER(acc)                                              \
  _Pragma("unroll")                                                  \
  for (int kq = 0; kq < 32; kq += 4) {                               \
    float4 xf[8];                                                    \
    _Pragma("unroll")                                                \
    for (int r = 0; r < 8; ++r)                                      \
      xf[r] = *(const float4*)&Xs[w * 8 + r][kq];                    \
    _Pragma("unroll")                                                \
    for (int u = 0; u < 4; ++u) {                                    \
      const float4 wv = *(const float4*)&Ws[kq + u][lane * 4];       \
      _Pragma("unroll")                                              \
      for (int r = 0; r < 8; ++r) {                                  \
        const float xv = (&xf[r].x)[u];                              \
        acc[r][0] = __fmaf_rn(xv, wv.x, acc[r][0]);                  \
        acc[r][1] = __fmaf_rn(xv, wv.y, acc[r][1]);                  \
        acc[r][2] = __fmaf_rn(xv, wv.z, acc[r][2]);                  \
        acc[r][3] = __fmaf_rn(xv, wv.w, acc[r][3]);                  \
      }                                                              \
    }                                                                \
  }

__global__ __launch_bounds__(256) void k_gemm_nt(
    const float* __restrict__ X, const float* __restrict__ WT,
    const float* __restrict__ bias, const float* __restrict__ th,
    float* __restrict__ OUT, int N) {
  __shared__ float Xs[32][36];   // pad 36 keeps b128 16B alignment
  __shared__ float Ws[32][256];
  const int tid = threadIdx.x;
  const int w = tid >> 6, lane = tid & 63;
  const size_t bm = (size_t)blockIdx.x * 32;
  const int bn = blockIdx.y * 256;
  float accA[8][4], accB[8][4];
#pragma unroll
  for (int r = 0; r < 8; ++r)
#pragma unroll
    for (int c = 0; c < 4; ++c) { accA[r][c] = 0.f; accB[r][c] = 0.f; }

  for (int k0 = 0; k0 < 512; k0 += 32) {
    {  // stage X tile: one float4/thread, coalesced rows
      const int row = tid >> 3, kq = (tid & 7) * 4;
      const float4 v = *(const float4*)&X[(bm + row) * 512 + k0 + kq];
      *(float4*)&Xs[row][kq] = v;
    }
    // stage W tile from WT rows: contiguous 1KB per wave, b128 LDS writes
    for (int t = tid; t < 2048; t += 256) {
      const int kk = t >> 6, n4 = (t & 63) * 4;
      const float4 v = *(const float4*)&WT[(size_t)(k0 + kk) * N + bn + n4];
      *(float4*)&Ws[kk][n4] = v;
    }
    __syncthreads();
    if (k0 < 384) { GEMM_INNER(accA); } else { GEMM_INNER(accB); }
    __syncthreads();
  }
  // epilogue: C = P1+P2; +bias; optional gate (bit-frozen sequence)
#pragma unroll
  for (int r = 0; r < 8; ++r) {
    const size_t orow = (bm + w * 8 + r) * (size_t)N + bn + lane * 4;
    float4 o;
    float* op = &o.x;
#pragma unroll
    for (int c = 0; c < 4; ++c) {
      const int col = bn + lane * 4 + c;
      const float v = fadd32(fadd32(accA[r][c], accB[r][c]), bias[col]);
      op[c] = th ? ((v >= th[col]) ? v : 0.f) : v;
    }
    *(float4*)&OUT[orow] = o;
  }
}

// ---------------- residual + LN (bit-frozen; O may alias F) ----------------
__global__ __launch_bounds__(256) void k_add_ln(
    const float* __restrict__ A, const float* F,
    const float* __restrict__ g, const float* __restrict__ bet,
    float* O, int nrows) {
  __shared__ float zb[4][512];
  const int w = threadIdx.x >> 6;
  const int lane = threadIdx.x & 63;
  const int wid = blockIdx.x * 4 + w;
  if (wid >= nrows) return;
  const size_t row = (size_t)wid * 512;
  float z[8];
#pragma unroll
  for (int k = 0; k < 8; ++k) {
    const int c = k * 64 + lane;
    z[k] = fadd32(A[row + c], F[row + c]);
    zb[w][c] = z[k];
  }
  const float m = fmul32(np_pairwise512(zb[w], lane), 1.f / 512.f);
  float d[8];
#pragma unroll
  for (int k = 0; k < 8; ++k) {
    d[k] = fsub32(z[k], m);
    zb[w][k * 64 + lane] = fmul32(d[k], d[k]);
  }
  const float var = fmul32(np_pairwise512(zb[w], lane), 1.f / 512.f);
  const float sdev = __fsqrt_rn(fadd32(var, 1e-5f));
#pragma unroll
  for (int k = 0; k < 8; ++k) {
    const int c = k * 64 + lane;
    O[row + c] = fadd32(fmul32(fdiv32(d[k], sdev), g[c]), bet[c]);
  }
}

// ---------------- mean-pool groups of 4 rows (bit-frozen) ----------------
__global__ __launch_bounds__(256) void k_pool4(
    const float* __restrict__ in, float* __restrict__ out) {
  const int idx = blockIdx.x * 256 + threadIdx.x;
  const int r = idx >> 9, c = idx & 511;
  const size_t base = (size_t)r * 2048 + c;
  const float s = fadd32(fadd32(fadd32(in[base], in[base + 512]), in[base + 1024]),
                         in[base + 1536]);
  out[idx] = fmul32(s, 0.25f);
}

// ---------------- transpose node weights: nwT[n][d][e] = nw[n][e][d] --------
__global__ __launch_bounds__(256) void k_transpose_nw(
    const float* __restrict__ nw, float* __restrict__ nwT) {
  const int idx = blockIdx.x * 256 + threadIdx.x;
  if (idx >= 15 * 4096) return;
  const int n = idx >> 12;
  const int e = (idx >> 6) & 63;
  const int d = idx & 63;
  nwT[(n << 12) + (d << 6) + e] = nw[idx];
}

// numpy einsum baseline-SSE model (bit-frozen).
#define NP_EINSUM64(inp, wp, out_)                                          \
  {                                                                         \
    float c0 = 0.f, c1 = 0.f, c2 = 0.f, c3 = 0.f;                           \
    _Pragma("unroll")                                                       \
    for (int q_ = 0; q_ < 4; ++q_) {                                        \
      const int b_ = 16 * q_;                                               \
      _Pragma("unroll")                                                     \
      for (int u_ = 3; u_ >= 0; --u_) {                                     \
        const int d0_ = b_ + 4 * u_;                                        \
        c0 = fadd32(fmul32(__shfl(inp, d0_ + 0), wp[(d0_ + 0) << 6]), c0);  \
        c1 = fadd32(fmul32(__shfl(inp, d0_ + 1), wp[(d0_ + 1) << 6]), c1);  \
        c2 = fadd32(fmul32(__shfl(inp, d0_ + 2), wp[(d0_ + 2) << 6]), c2);  \
        c3 = fadd32(fmul32(__shfl(inp, d0_ + 3), wp[(d0_ + 3) << 6]), c3);  \
      }                                                                     \
    }                                                                       \
    out_ = fadd32(fadd32(c0, c1), fadd32(c2, c3));                          \
  }

// ---------------- fused spiking tree (bit-frozen) ----------------
__global__ __launch_bounds__(256) void k_tree(
    const float* __restrict__ QKV, const float* __restrict__ nwT,
    const float* __restrict__ nb, const float* __restrict__ th,
    const float* __restrict__ tau, const float* __restrict__ vr,
    float* __restrict__ TK, float* __restrict__ TV) {
  __shared__ float st0[8][8][64];
  __shared__ float st1[4][8][64];
  __shared__ float st2[2][8][64];
  __shared__ float st3[8][64];
  __shared__ float outA[8][8][64];
  __shared__ float outB[4][8][64];
  const int tid = threadIdx.x, w = tid >> 6, lane = tid & 63;
  const int sq = blockIdx.x & 3, bh = blockIdx.x >> 2;
  const int b = bh >> 3, h = bh & 7;
  for (int pass = 0; pass < 2; ++pass) {
    const int koff = 512 + pass * 512;
    for (int r = w; r < 64; r += 4) {
      const int n = r >> 3, sl = r & 7, sg = sq * 8 + sl;
      const float inp = QKV[((size_t)(b * 512 + n * 32 + sg)) * 1536 + koff + h * 64 + lane];
      const int node = 7 + n, pc = node * 64 + lane;
      const float* wp = nwT + node * 4096 + lane;
      float tot;
      NP_EINSUM64(inp, wp, tot);
      const float proj = fadd32(tot, nb[pc]);
      const float v = pass ? fadd32(fmul32(tau[pc], st0[n][sl][lane]), proj) : proj;
      const bool sp = v >= th[pc];
      if (!pass) st0[n][sl][lane] = sp ? vr[pc] : v;
      outA[n][sl][lane] = sp ? proj : 0.f;
    }
    __syncthreads();
    for (int r = w; r < 32; r += 4) {
      const int n = r >> 3, sl = r & 7;
      const float inp = fmul32(0.5f, fadd32(outA[2 * n][sl][lane], outA[2 * n + 1][sl][lane]));
      const int node = 3 + n, pc = node * 64 + lane;
      const float* wp = nwT + node * 4096 + lane;
      float tot;
      NP_EINSUM64(inp, wp, tot);
      const float proj = fadd32(tot, nb[pc]);
      const float v = pass ? fadd32(fmul32(tau[pc], st1[n][sl][lane]), proj) : proj;
      const bool sp = v >= th[pc];
      if (!pass) st1[n][sl][lane] = sp ? vr[pc] : v;
      outB[n][sl][lane] = sp ? proj : 0.f;
    }
    __syncthreads();
    for (int r = w; r < 16; r += 4) {
      const int n = r >> 3, sl = r & 7;
      const float inp = fmul32(0.5f, fadd32(outB[2 * n][sl][lane], outB[2 * n + 1][sl][lane]));
      const int node = 1 + n, pc = node * 64 + lane;
      const float* wp = nwT + node * 4096 + lane;
      float tot;
      NP_EINSUM64(inp, wp, tot);
      const float proj = fadd32(tot, nb[pc]);
      const float v = pass ? fadd32(fmul32(tau[pc], st2[n][sl][lane]), proj) : proj;
      const bool sp = v >= th[pc];
      if (!pass) st2[n][sl][lane] = sp ? vr[pc] : v;
      outA[n][sl][lane] = sp ? proj : 0.f;
    }
    __syncthreads();
    for (int r = w; r < 8; r += 4) {
      const int sl = r & 7, sg = sq * 8 + sl;
      const float inp = fmul32(0.5f, fadd32(outA[0][sl][lane], outA[1][sl][lane]));
      const int pc = lane;
      const float* wp = nwT + lane;
      float tot;
      NP_EINSUM64(inp, wp, tot);
      const float proj = fadd32(tot, nb[pc]);
      const float v = pass ? fadd32(fmul32(tau[pc], st3[sl][lane]), proj) : proj;
      const bool sp = v >= th[pc];
      if (!pass) st3[sl][lane] = sp ? vr[pc] : v;
      float* dst = pass ? TV : TK;
      dst[((size_t)bh * 32 + sg) * 64 + lane] = sp ? proj : 0.f;
    }
    __syncthreads();
  }
}

// ---------------- attention (post-gate, relaxed; fp32 chains) ----------------
__global__ __launch_bounds__(256) void k_attn(
    const float* __restrict__ qkv, const float* __restrict__ treeK,
    const float* __restrict__ treeV, float* __restrict__ attn) {
  __shared__ float Ks[32][65];
  __shared__ float Vs[32][64];
  __shared__ float qs[4][64];
  const int tid = threadIdx.x;
  const int bh = blockIdx.x >> 7;
  const int lq0 = (blockIdx.x & 127) * 4;
  const int b = bh >> 3, h = bh & 7;
  for (int i = tid; i < 2048; i += 256) {
    const int j = i >> 6, d = i & 63;
    Ks[j][d] = treeK[((size_t)bh * 32 + j) * 64 + d];
    Vs[j][d] = treeV[((size_t)bh * 32 + j) * 64 + d];
  }
  {
    const int w = tid >> 6, d = tid & 63;
    qs[w][d] = qkv[((size_t)(b * 512) + lq0 + w) * 1536 + h * 64 + d];
  }
  __syncthreads();
  const int w = tid >> 6;
  const int lane = tid & 63;
  const int j = lane & 31;
  float sc = 0.f;
#pragma unroll
  for (int d = 0; d < 64; ++d) sc = __fmaf_rn(qs[w][d], Ks[j][d], sc);
  sc = fmul32(sc, 0.125f);
  float m = sc;
#pragma unroll
  for (int k = 1; k < 32; k <<= 1) m = fmaxf(m, __shfl_xor(m, k));
  float p = expf(fsub32(sc, m));
  float sum = p;
#pragma unroll
  for (int k = 1; k < 32; k <<= 1) sum += __shfl_xor(sum, k);
  p = fdiv32(p, sum);
  float acc = 0.f;
#pragma unroll
  for (int jj = 0; jj < 32; ++jj)
    acc = __fmaf_rn(__shfl(p, jj), Vs[jj][lane], acc);
  attn[((size_t)(b * 512) + lq0 + w) * 512 + h * 64 + lane] = acc;
}

// ---------------- linear interpolation 512 -> 4096 rows ----------------
__global__ __launch_bounds__(256) void k_interp(
    const float* __restrict__ rows, float* __restrict__ out) {
  const int wid = blockIdx.x * 4 + (threadIdx.x >> 6);  // b*4096+s
  const int lane = threadIdx.x & 63;
  const int b = wid >> 12;
  const int s = wid & 4095;
  const double src = fmax(((double)s + 0.5) * 0.125 - 0.5, 0.0);
  const int i0 = (int)src;
  const int i1 = min(i0 + 1, 511);
  const double w1 = src - (double)i0;
  const double w0 = 1.0 - w1;
  const size_t r0 = ((size_t)b * 512 + i0) * 512;
  const size_t r1 = ((size_t)b * 512 + i1) * 512;
  const size_t o = (size_t)wid * 512;
#pragma unroll
  for (int k = 0; k < 2; ++k) {
    const int c4 = lane + 64 * k;
    const float4 a = *reinterpret_cast<const float4*>(&rows[r0 + (size_t)c4 * 4]);
    const float4 c = *reinterpret_cast<const float4*>(&rows[r1 + (size_t)c4 * 4]);
    float4 r;
    r.x = (float)((double)a.x * w0 + (double)c.x * w1);
    r.y = (float)((double)a.y * w0 + (double)c.y * w1);
    r.z = (float)((double)a.z * w0 + (double)c.z * w1);
    r.w = (float)((double)a.w * w0 + (double)c.w * w1);
    *reinterpret_cast<float4*>(&out[o + (size_t)c4 * 4]) = r;
  }
}

extern "C" void kernel_launch(void* const* d_in, const int* in_sizes, int n_in,
                              void* d_out, int out_size, void* d_ws, size_t ws_size,
                              hipStream_t stream) {
  const int*   text    = (const int*)d_in[0];
  const float* pe      = (const float*)d_in[1];
  const float* id_w    = (const float*)d_in[2];
  const float* id_b    = (const float*)d_in[3];
  const float* eg      = (const float*)d_in[4];
  const float* ebeta   = (const float*)d_in[5];
  const float* sub_w   = (const float*)d_in[6];
  const float* sub_b   = (const float*)d_in[7];
  const float* sub_th  = (const float*)d_in[8];
  const float* sub_ng  = (const float*)d_in[11];
  const float* sub_nb  = (const float*)d_in[12];
  const float* word_w  = (const float*)d_in[13];
  const float* word_b  = (const float*)d_in[14];
  const float* word_th = (const float*)d_in[15];
  const float* word_ng = (const float*)d_in[18];
  const float* word_nb = (const float*)d_in[19];
  const float* qkv_w   = (const float*)d_in[20];
  const float* qkv_b   = (const float*)d_in[21];
  const float* node_w  = (const float*)d_in[22];
  const float* node_b  = (const float*)d_in[23];
  const float* node_th = (const float*)d_in[24];
  const float* node_tau= (const float*)d_in[25];
  const float* node_vr = (const float*)d_in[26];
  const float* out_ng  = (const float*)d_in[27];
  const float* out_nb  = (const float*)d_in[28];

  float* O   = (float*)d_out;   // 67,108,864 floats
  float* WSF = (float*)d_ws;

  // d_out regions (floats)
  float* FU  = O;               // fused1 -> sub, in place [0 : 33554432)
  float* GZ1 = O + 33554432;    // sub gated proj [33554432 : 67108864)
  float* WD  = O + 33554432;    // word [33554432 : 41943040)
  float* GZ2 = O + 41943040;    // word gated proj (dead before qkv write)
  float* QKV = O + 41943040;    // qkv  [41943040 : 67108864)

  // ws regions (floats) — peak 19,197,952 floats = 76.8 MB
  float* W1   = WSF;            // [0 : 8388608)
  float* NWT  = WSF + 8388608;  // 61440
  float* TK   = WSF + 8450048;  // 524288
  float* TV   = WSF + 8974336;  // 524288
  float* ROWS = WSF + 9498624;  // 8388608
  float* WTs  = WSF + 17887232; // 262144  (sub_w^T  [512][512])
  float* WTw  = WSF + 18149376; // 262144  (word_w^T [512][512])
  float* WTq  = WSF + 18411520; // 786432  (qkv_w^T  [512][1536])
  float* ATT  = WSF;            // reuses W1 (dead after word LN)

  // 0. weight transposes (independent of activations)
  k_transpose_w<<<dim3(16, 16), 256, 0, stream>>>(sub_w, WTs, 512);
  k_transpose_w<<<dim3(16, 16), 256, 0, stream>>>(word_w, WTw, 512);
  k_transpose_w<<<dim3(48, 16), 256, 0, stream>>>(qkv_w, WTq, 1536);
  k_transpose_nw<<<240, 256, 0, stream>>>(node_w, NWT);
  // 1. embed + LN + pool2 -> FU
  k_embed<<<16384, 256, 0, stream>>>(text, pe, id_w, id_b, eg, ebeta, FU);
  // 2. GZ1 = gate(FU @ sub_w^T + b)
  k_gemm_nt<<<dim3(2048, 2), 256, 0, stream>>>(FU, WTs, sub_b, sub_th, GZ1, 512);
  // 3. sub = LN(GZ1 + FU) -> FU in place
  k_add_ln<<<16384, 256, 0, stream>>>(GZ1, FU, sub_ng, sub_nb, FU, 65536);
  // 4. W1 = pool4(sub)
  k_pool4<<<32768, 256, 0, stream>>>(FU, W1);
  // 5. GZ2 = gate(W1 @ word_w^T + b)
  k_gemm_nt<<<dim3(512, 2), 256, 0, stream>>>(W1, WTw, word_b, word_th, GZ2, 512);
  // 6. word = LN(GZ2 + W1) -> WD
  k_add_ln<<<4096, 256, 0, stream>>>(GZ2, W1, word_ng, word_nb, WD, 16384);
  // 7. QKV = WD @ qkv_w^T + b
  k_gemm_nt<<<dim3(512, 6), 256, 0, stream>>>(WD, WTq, qkv_b, nullptr, QKV, 1536);
  // 8. fused spiking tree -> TK, TV
  k_tree<<<1024, 256, 0, stream>>>(QKV, NWT, node_b, node_th,
                                   node_tau, node_vr, TK, TV);
  // 9. attention -> ATT (reuses dead W1 space)
  k_attn<<<32768, 256, 0, stream>>>(QKV, TK, TV, ATT);
  // 10. rows = LN(ATT + word) -> ROWS
  k_add_ln<<<4096, 256, 0, stream>>>(ATT, WD, out_ng, out_nb, ROWS, 16384);
  // 11. interpolate 512 -> 4096 rows, full fp32 d_out overwrite
  k_interp<<<32768, 256, 0, stream>>>(ROWS, O);
}